// Round 2
// baseline (607.651 us; speedup 1.0000x reference)
//
#include <hip/hip_runtime.h>

// ---------------------------------------------------------------------------
// SelectedUnitsHead (AlphaStar-style pointer head), MI355X / gfx950
// B=256 rows, E=512 entities, 64 autoregressive steps.
// One persistent block per batch row (rows are independent).
// JAX threefry2x32 RNG reproduced bit-exactly (partitionable layout).
// d_out is FLOAT32 (established round 1: units bf16-pair 0x4400_0000 artifact
// decomposed exactly as fp32 512.0 at a logit position).
// ---------------------------------------------------------------------------

#define JAX_PARTITIONABLE 1   // flip to 0 if units IDs mismatch (old JAX RNG layout)

typedef unsigned int u32;
typedef unsigned short u16;

#define NB 256
#define NE 512
#define NC 256
#define NT 64
#define KPW 20                 // kp row stride in u32 words (= 40 bf16, 80 B, 16B-aligned)

#define OFF_UNITS 8388608      // 256*64*512   (fp32 elements)
#define OFF_AR    8404992      // + 256*64     (fp32 elements)

// ws layout (floats): [0,8192) Wq ; [8192,8448) cvec ; [8448,8448+65536) xf0
#define WS_WQ  0
#define WS_CV  8192
#define WS_XF0 8448

struct U2 { u32 a, b; };

__host__ __device__ constexpr u32 rotl32(u32 x, int r) {
  return (x << r) | (x >> (32 - r));
}

// JAX threefry2x32: 20 rounds, key schedule parity 0x1BD11BDA
__host__ __device__ constexpr U2 tf2x32(u32 k0, u32 k1, u32 x0, u32 x1) {
  u32 ks2 = k0 ^ k1 ^ 0x1BD11BDAu;
  x0 += k0; x1 += k1;
  x0 += x1; x1 = rotl32(x1, 13); x1 ^= x0;
  x0 += x1; x1 = rotl32(x1, 15); x1 ^= x0;
  x0 += x1; x1 = rotl32(x1, 26); x1 ^= x0;
  x0 += x1; x1 = rotl32(x1, 6);  x1 ^= x0;
  x0 += k1; x1 += ks2 + 1u;
  x0 += x1; x1 = rotl32(x1, 17); x1 ^= x0;
  x0 += x1; x1 = rotl32(x1, 29); x1 ^= x0;
  x0 += x1; x1 = rotl32(x1, 16); x1 ^= x0;
  x0 += x1; x1 = rotl32(x1, 24); x1 ^= x0;
  x0 += ks2; x1 += k0 + 2u;
  x0 += x1; x1 = rotl32(x1, 13); x1 ^= x0;
  x0 += x1; x1 = rotl32(x1, 15); x1 ^= x0;
  x0 += x1; x1 = rotl32(x1, 26); x1 ^= x0;
  x0 += x1; x1 = rotl32(x1, 6);  x1 ^= x0;
  x0 += k0; x1 += k1 + 3u;
  x0 += x1; x1 = rotl32(x1, 17); x1 ^= x0;
  x0 += x1; x1 = rotl32(x1, 29); x1 ^= x0;
  x0 += x1; x1 = rotl32(x1, 16); x1 ^= x0;
  x0 += x1; x1 = rotl32(x1, 24); x1 ^= x0;
  x0 += k1; x1 += ks2 + 4u;
  x0 += x1; x1 = rotl32(x1, 13); x1 ^= x0;
  x0 += x1; x1 = rotl32(x1, 15); x1 ^= x0;
  x0 += x1; x1 = rotl32(x1, 26); x1 ^= x0;
  x0 += x1; x1 = rotl32(x1, 6);  x1 ^= x0;
  x0 += ks2; x1 += k0 + 5u;
  return U2{x0, x1};
}

struct KeyTab { u32 s0[NT]; u32 s1[NT]; };

// Key chain from jax.random.key(42): per step rng,sub = split(rng).
__host__ __device__ constexpr KeyTab make_tab() {
  KeyTab t{};
  u32 k0 = 0u, k1 = 42u;
  for (int i = 0; i < NT; ++i) {
#if JAX_PARTITIONABLE
    U2 nk = tf2x32(k0, k1, 0u, 0u);   // child 0 -> new rng
    U2 sb = tf2x32(k0, k1, 0u, 1u);   // child 1 -> sub
#else
    U2 r02 = tf2x32(k0, k1, 0u, 2u);
    U2 r13 = tf2x32(k0, k1, 1u, 3u);
    U2 nk{r02.a, r13.a};
    U2 sb{r02.b, r13.b};
#endif
    t.s0[i] = sb.a; t.s1[i] = sb.b;
    k0 = nk.a; k1 = nk.b;
  }
  return t;
}

__constant__ KeyTab SUBTAB = make_tab();

// gumbel = -log(-log(uniform(sub, (B,E), 1e-20, 1.0))) at flat index jf
__device__ __forceinline__ float gumbel_draw(u32 k0, u32 k1, u32 jf) {
#if JAX_PARTITIONABLE
  U2 v = tf2x32(k0, k1, 0u, jf);
  u32 bits = v.a ^ v.b;
#else
  u32 bits;
  if (jf < 65536u) { U2 v = tf2x32(k0, k1, jf, jf + 65536u); bits = v.a; }
  else             { U2 v = tf2x32(k0, k1, jf - 65536u, jf); bits = v.b; }
#endif
  float f = __uint_as_float((bits >> 9) | 0x3f800000u) - 1.0f;
  float u = f + 1e-20f;
  u = fmaxf(u, 1e-20f);
  return -logf(-logf(u));
}

__device__ __forceinline__ u16 f2bf(float f) {   // RNE fp32 -> bf16 (LDS kp pack)
  u32 u = __float_as_uint(f);
  u += 0x7fffu + ((u >> 16) & 1u);
  return (u16)(u >> 16);
}

// ---------------------------------------------------------------------------
// K1: xf0 = ar0@W1 + b1 + relu(um[a]@Wf + bf)   (blocks 0..255, one row each)
//     Wq  = Wp@W1                                (blocks 256..287, one row each)
//     cvec= bp@W1                                (block 288)
// ---------------------------------------------------------------------------
__global__ __launch_bounds__(256) void suh_prep(
    const float* __restrict__ ar0, const int* __restrict__ act,
    const float* __restrict__ Wf, const float* __restrict__ bfv,
    const float* __restrict__ W1, const float* __restrict__ b1,
    const float* __restrict__ Wp, const float* __restrict__ bp,
    const float* __restrict__ umt, float* __restrict__ ws)
{
  __shared__ float lvec[1024];
  __shared__ float lum[256];
  const int t = threadIdx.x;
  const int bid = blockIdx.x;

  if (bid < NB) {
    const int b = bid;
    for (int i = t; i < 1024; i += 256) lvec[i] = ar0[b * 1024 + i];
    const int a = act[b];
    lum[t] = umt[a * 256 + t];
    __syncthreads();
    float acc = b1[t];
    #pragma unroll 8
    for (int k = 0; k < 1024; ++k) acc = fmaf(lvec[k], W1[k * 256 + t], acc);
    float fe = bfv[t];
    #pragma unroll 4
    for (int k = 0; k < 256; ++k) fe = fmaf(lum[k], Wf[k * 256 + t], fe);
    ws[WS_XF0 + b * 256 + t] = acc + fmaxf(fe, 0.0f);
  } else if (bid < NB + 32) {
    const int r = bid - NB;
    for (int i = t; i < 1024; i += 256) lvec[i] = Wp[r * 1024 + i];
    __syncthreads();
    float acc = 0.0f;
    #pragma unroll 8
    for (int k = 0; k < 1024; ++k) acc = fmaf(lvec[k], W1[k * 256 + t], acc);
    ws[WS_WQ + r * 256 + t] = acc;
  } else {
    for (int i = t; i < 1024; i += 256) lvec[i] = bp[i];
    __syncthreads();
    float acc = 0.0f;
    #pragma unroll 8
    for (int k = 0; k < 1024; ++k) acc = fmaf(lvec[k], W1[k * 256 + t], acc);
    ws[WS_CV + t] = acc;
  }
}

// ---------------------------------------------------------------------------
// K2: one block per batch row; runs all 64 autoregressive steps.
// ---------------------------------------------------------------------------
__global__ __launch_bounds__(512, 1) void suh_main(
    const float* __restrict__ ar0, const int* __restrict__ act,
    const float* __restrict__ emb, const float* __restrict__ Wk,
    const float* __restrict__ bk, const float* __restrict__ W2,
    const float* __restrict__ b2, const float* __restrict__ Wx,
    const float* __restrict__ Wh, const float* __restrict__ bl,
    const float* __restrict__ Wp, const float* __restrict__ bp,
    const float* __restrict__ selt, const float* __restrict__ ws,
    float* __restrict__ outp)
{
  const int b = blockIdx.x;
  const int t = threadIdx.x;
  const int a = act[b];
  const float sel = selt[a];
  float* outL = outp;
  float* outU = outp + OFF_UNITS;
  float* outA = outp + OFF_AR;

  if (sel == 0.0f) {
    // select==0: all three outputs for this row are exactly zero.
    float4 z4 = {0.0f, 0.0f, 0.0f, 0.0f};
    float4* pl = (float4*)(outL + (size_t)b * 32768);
    for (int i = t; i < 8192; i += 512) pl[i] = z4;
    if (t < 16) ((float4*)(outU + b * 64))[t] = z4;
    if (t < 256) ((float4*)(outA + b * 1024))[t] = z4;
    return;
  }

  __shared__ __align__(16) u32 kpu[NE * KPW];   // key_proj row, bf16-packed (40 KB)
  __shared__ __align__(16) float xf[256];       // func_embed + x_t
  __shared__ float maskv[NE];
  __shared__ float red[512];
  __shared__ __align__(16) float hbuf[32];
  __shared__ float cbuf[32];
  __shared__ float z2s[32];
  __shared__ __align__(16) float outv[32];
  __shared__ float sacc[32];
  __shared__ float cvs[256];
  __shared__ float bls[128];
  __shared__ float b2s[32];
  __shared__ float wmaxp[8], wsump[8], wargv[8];
  __shared__ int wargi[8];

  // per-thread register-resident weights
  const int hh2 = t & 31, kc = t >> 5;   // phase A: (hh, k-chunk of 16)
  float w2r[16];
  #pragma unroll
  for (int i = 0; i < 16; ++i) w2r[i] = W2[(kc * 16 + i) * 32 + hh2];

  const int gg = t & 127, rc = t >> 7;   // phase B: (gate col, r-chunk of 8)
  float wxr[8], whr[8];
  #pragma unroll
  for (int i = 0; i < 8; ++i) {
    wxr[i] = Wx[(rc * 8 + i) * 128 + gg];
    whr[i] = Wh[(rc * 8 + i) * 128 + gg];
  }
  float wqr[32];
  if (t < 256) {
    #pragma unroll
    for (int r = 0; r < 32; ++r) wqr[r] = ws[WS_WQ + r * 256 + t];
    xf[t] = ws[WS_XF0 + b * 256 + t];
    cvs[t] = ws[WS_CV + t];
  }
  if (t < 128) bls[t] = bl[t];
  if (t < 32) { b2s[t] = b2[t]; hbuf[t] = 0.0f; cbuf[t] = 0.0f; sacc[t] = 0.0f; }
  maskv[t] = 1.0f;

  // key_proj row e=t: kp[e][h] = sum_c emb[b,e,c]*Wk[c,h] + bk[h]
  {
    float acc[32];
    #pragma unroll
    for (int h = 0; h < 32; ++h) acc[h] = bk[h];
    const float4* erow = (const float4*)(emb + (size_t)b * (NE * NC) + (size_t)t * NC);
    for (int c4 = 0; c4 < 64; ++c4) {
      float4 ev = erow[c4];
      const float* wr = Wk + c4 * 4 * 32;
      #pragma unroll
      for (int h = 0; h < 32; ++h) acc[h] = fmaf(ev.x, wr[h], acc[h]);
      #pragma unroll
      for (int h = 0; h < 32; ++h) acc[h] = fmaf(ev.y, wr[32 + h], acc[h]);
      #pragma unroll
      for (int h = 0; h < 32; ++h) acc[h] = fmaf(ev.z, wr[64 + h], acc[h]);
      #pragma unroll
      for (int h = 0; h < 32; ++h) acc[h] = fmaf(ev.w, wr[96 + h], acc[h]);
    }
    u32* kr = &kpu[t * KPW];
    #pragma unroll
    for (int w = 0; w < 16; ++w) {
      u32 lo = (u32)f2bf(acc[2 * w]);
      u32 hi = (u32)f2bf(acc[2 * w + 1]);
      kr[w] = lo | (hi << 16);
    }
  }
  __syncthreads();

  for (int step = 0; step < NT; ++step) {
    const u32 sk0 = SUBTAB.s0[step], sk1 = SUBTAB.s1[step];
    const float gum = gumbel_draw(sk0, sk1, (u32)(b * 512 + t));

    // ---- A: z2 partials: relu(xf) @ W2 -------------------------------------
    {
      float pa = 0.0f;
      const float* xk = &xf[kc * 16];
      #pragma unroll
      for (int i = 0; i < 16; ++i) pa = fmaf(fmaxf(xk[i], 0.0f), w2r[i], pa);
      red[kc * 32 + hh2] = pa;
    }
    __syncthreads();                                   // 1
    if (t < 32) {
      float z = b2s[t];
      #pragma unroll
      for (int i = 0; i < 16; ++i) z += red[i * 32 + t];
      z2s[t] = z;
    }
    __syncthreads();                                   // 2

    // ---- B: LSTM gate partials: z2@Wx + h@Wh -------------------------------
    {
      float pb = 0.0f;
      #pragma unroll
      for (int i = 0; i < 8; ++i) {
        const int r = rc * 8 + i;
        pb = fmaf(z2s[r], wxr[i], pb);
        pb = fmaf(hbuf[r], whr[i], pb);
      }
      red[rc * 128 + gg] = pb;
    }
    __syncthreads();                                   // 3
    if (t < 32) {
      float zi = bls[t], zf = bls[32 + t], zg = bls[64 + t], zo = bls[96 + t];
      #pragma unroll
      for (int q = 0; q < 4; ++q) {
        zi += red[q * 128 + t];
        zf += red[q * 128 + 32 + t];
        zg += red[q * 128 + 64 + t];
        zo += red[q * 128 + 96 + t];
      }
      const float si = 1.0f / (1.0f + expf(-zi));
      const float sf = 1.0f / (1.0f + expf(-zf));
      const float so = 1.0f / (1.0f + expf(-zo));
      const float cN = sf * cbuf[t] + si * tanhf(zg);
      const float hN = so * tanhf(cN);
      cbuf[t] = cN; hbuf[t] = hN;
    }
    __syncthreads();                                   // 4

    // ---- C: y = kp[e]·h, softmax, +gumbel, argmax --------------------------
    float yv = 0.0f;
    {
      const u32* kr = &kpu[t * KPW];
      #pragma unroll
      for (int q = 0; q < 4; ++q) {
        uint4 kv = *((const uint4*)(kr + q * 4));
        float4 hv0 = *((const float4*)&hbuf[q * 8]);
        float4 hv1 = *((const float4*)&hbuf[q * 8 + 4]);
        yv = fmaf(__uint_as_float(kv.x << 16), hv0.x, yv);
        yv = fmaf(__uint_as_float(kv.x & 0xffff0000u), hv0.y, yv);
        yv = fmaf(__uint_as_float(kv.y << 16), hv0.z, yv);
        yv = fmaf(__uint_as_float(kv.y & 0xffff0000u), hv0.w, yv);
        yv = fmaf(__uint_as_float(kv.z << 16), hv1.x, yv);
        yv = fmaf(__uint_as_float(kv.z & 0xffff0000u), hv1.y, yv);
        yv = fmaf(__uint_as_float(kv.w << 16), hv1.z, yv);
        yv = fmaf(__uint_as_float(kv.w & 0xffff0000u), hv1.w, yv);
      }
    }
    const float y2 = yv * maskv[t];
    outL[(size_t)b * 32768 + step * 512 + t] = y2;     // logits output (fp32)

    float m = y2;
    #pragma unroll
    for (int s = 1; s < 64; s <<= 1) m = fmaxf(m, __shfl_xor(m, s));
    if ((t & 63) == 0) wmaxp[t >> 6] = m;
    __syncthreads();                                   // 5
    float mx = wmaxp[0];
    #pragma unroll
    for (int i = 1; i < 8; ++i) mx = fmaxf(mx, wmaxp[i]);
    const float ev = expf(y2 - mx);
    float sv = ev;
    #pragma unroll
    for (int s = 1; s < 64; s <<= 1) sv += __shfl_xor(sv, s);
    if ((t & 63) == 0) wsump[t >> 6] = sv;
    __syncthreads();                                   // 6
    float Z = 0.0f;
    #pragma unroll
    for (int i = 0; i < 8; ++i) Z += wsump[i];

    float val = ev / Z + gum;
    int idx = t;
    #pragma unroll
    for (int s = 1; s < 64; s <<= 1) {
      const float vo = __shfl_xor(val, s);
      const int io = __shfl_xor(idx, s);
      if (vo > val || (vo == val && io < idx)) { val = vo; idx = io; }
    }
    if ((t & 63) == 0) { wargv[t >> 6] = val; wargi[t >> 6] = idx; }
    __syncthreads();                                   // 7
    float bv = wargv[0]; int id = wargi[0];
    #pragma unroll
    for (int i = 1; i < 8; ++i) {
      if (wargv[i] > bv || (wargv[i] == bv && wargi[i] < id)) { bv = wargv[i]; id = wargi[i]; }
    }

    // ---- D: gather selected row, mask, feedback ----------------------------
    if (t < 32) {
      const u32 w = kpu[id * KPW + (t >> 1)];
      const float kv = __uint_as_float((t & 1) ? (w & 0xffff0000u) : (w << 16));
      const float ov = kv - 0.001953125f;       // - mean(one_hot) = 1/512
      outv[t] = ov;
      sacc[t] += ov;
    }
    if (t == 0) {
      maskv[id] = 0.0f;
      outU[b * 64 + step] = (float)id;          // units output (fp32)
    }
    __syncthreads();                                   // 8
    if (t < 256) {
      float dx = cvs[t];
      #pragma unroll
      for (int r = 0; r < 32; ++r) dx = fmaf(outv[r], wqr[r], dx);
      xf[t] += dx;
    }
    __syncthreads();                                   // 9
  }

  // epilogue: ar = ar0 + (sum_t out_t)@Wp + 64*bp  (select==1 here)
  for (int j = t; j < 1024; j += 512) {
    float acc2 = ar0[b * 1024 + j] + 64.0f * bp[j];
    #pragma unroll 8
    for (int r = 0; r < 32; ++r) acc2 = fmaf(sacc[r], Wp[r * 1024 + j], acc2);
    outA[b * 1024 + j] = acc2;
  }
}

extern "C" void kernel_launch(void* const* d_in, const int* in_sizes, int n_in,
                              void* d_out, int out_size, void* d_ws, size_t ws_size,
                              hipStream_t stream)
{
  (void)in_sizes; (void)n_in; (void)out_size; (void)ws_size;
  const float* ar0 = (const float*)d_in[0];
  const int*   act = (const int*)d_in[1];
  const float* emb = (const float*)d_in[2];
  const float* Wf  = (const float*)d_in[3];
  const float* bfv = (const float*)d_in[4];
  const float* Wk  = (const float*)d_in[5];
  const float* bk  = (const float*)d_in[6];
  const float* W1  = (const float*)d_in[7];
  const float* b1  = (const float*)d_in[8];
  const float* W2  = (const float*)d_in[9];
  const float* b2  = (const float*)d_in[10];
  const float* Wx  = (const float*)d_in[11];
  const float* Wh  = (const float*)d_in[12];
  const float* bl  = (const float*)d_in[13];
  const float* Wp  = (const float*)d_in[14];
  const float* bp  = (const float*)d_in[15];
  const float* umt = (const float*)d_in[16];
  const float* selt = (const float*)d_in[17];
  float* ws = (float*)d_ws;
  float* outp = (float*)d_out;

  suh_prep<<<dim3(289), dim3(256), 0, stream>>>(ar0, act, Wf, bfv, W1, b1, Wp, bp, umt, ws);
  suh_main<<<dim3(256), dim3(512), 0, stream>>>(ar0, act, emb, Wk, bk, W2, b2, Wx, Wh,
                                                bl, Wp, bp, selt, ws, outp);
}

// Round 3
// 558.888 us; speedup vs baseline: 1.0872x; 1.0872x over previous
//
#include <hip/hip_runtime.h>

// ---------------------------------------------------------------------------
// SelectedUnitsHead (AlphaStar-style pointer head), MI355X / gfx950
// B=256 rows, E=512 entities, 64 autoregressive steps.
// One persistent block (512 thr) per batch row. d_out is fp32 (est. round 1).
// v3: 5 barriers/step (was 9); LSTM fully in wave0 registers+shuffles;
//     Wq in LDS (kills the round-2 VGPR spill, VGPR was 68 => reloads);
//     kp init via v_dot2_f32_f16; kp stored f16 (better than bf16 r2).
// ---------------------------------------------------------------------------

#define JAX_PARTITIONABLE 1

typedef unsigned int u32;
typedef _Float16 half2v __attribute__((ext_vector_type(2)));

#define NB 256
#define NE 512
#define NT 64
#define KPW 40                 // kp row stride in halves (80 B, 16B-aligned)

#define OFF_UNITS 8388608      // 256*64*512   (fp32 elements)
#define OFF_AR    8404992      // + 256*64     (fp32 elements)

// ws layout (float units): Wq[8192] | cvec[256] | xf0[65536] | wk2[4096 u32]
#define WS_WQ   0
#define WS_CV   8192
#define WS_XF0  8448
#define WS_WK2  73984

struct U2 { u32 a, b; };

__host__ __device__ constexpr u32 rotl32(u32 x, int r) {
  return (x << r) | (x >> (32 - r));
}

__host__ __device__ constexpr U2 tf2x32(u32 k0, u32 k1, u32 x0, u32 x1) {
  u32 ks2 = k0 ^ k1 ^ 0x1BD11BDAu;
  x0 += k0; x1 += k1;
  x0 += x1; x1 = rotl32(x1, 13); x1 ^= x0;
  x0 += x1; x1 = rotl32(x1, 15); x1 ^= x0;
  x0 += x1; x1 = rotl32(x1, 26); x1 ^= x0;
  x0 += x1; x1 = rotl32(x1, 6);  x1 ^= x0;
  x0 += k1; x1 += ks2 + 1u;
  x0 += x1; x1 = rotl32(x1, 17); x1 ^= x0;
  x0 += x1; x1 = rotl32(x1, 29); x1 ^= x0;
  x0 += x1; x1 = rotl32(x1, 16); x1 ^= x0;
  x0 += x1; x1 = rotl32(x1, 24); x1 ^= x0;
  x0 += ks2; x1 += k0 + 2u;
  x0 += x1; x1 = rotl32(x1, 13); x1 ^= x0;
  x0 += x1; x1 = rotl32(x1, 15); x1 ^= x0;
  x0 += x1; x1 = rotl32(x1, 26); x1 ^= x0;
  x0 += x1; x1 = rotl32(x1, 6);  x1 ^= x0;
  x0 += k0; x1 += k1 + 3u;
  x0 += x1; x1 = rotl32(x1, 17); x1 ^= x0;
  x0 += x1; x1 = rotl32(x1, 29); x1 ^= x0;
  x0 += x1; x1 = rotl32(x1, 16); x1 ^= x0;
  x0 += x1; x1 = rotl32(x1, 24); x1 ^= x0;
  x0 += k1; x1 += ks2 + 4u;
  x0 += x1; x1 = rotl32(x1, 13); x1 ^= x0;
  x0 += x1; x1 = rotl32(x1, 15); x1 ^= x0;
  x0 += x1; x1 = rotl32(x1, 26); x1 ^= x0;
  x0 += x1; x1 = rotl32(x1, 6);  x1 ^= x0;
  x0 += ks2; x1 += k0 + 5u;
  return U2{x0, x1};
}

struct KeyTab { u32 s0[NT]; u32 s1[NT]; };

__host__ __device__ constexpr KeyTab make_tab() {
  KeyTab t{};
  u32 k0 = 0u, k1 = 42u;
  for (int i = 0; i < NT; ++i) {
#if JAX_PARTITIONABLE
    U2 nk = tf2x32(k0, k1, 0u, 0u);
    U2 sb = tf2x32(k0, k1, 0u, 1u);
#else
    U2 r02 = tf2x32(k0, k1, 0u, 2u);
    U2 r13 = tf2x32(k0, k1, 1u, 3u);
    U2 nk{r02.a, r13.a};
    U2 sb{r02.b, r13.b};
#endif
    t.s0[i] = sb.a; t.s1[i] = sb.b;
    k0 = nk.a; k1 = nk.b;
  }
  return t;
}

__constant__ KeyTab SUBTAB = make_tab();

__device__ __forceinline__ float gumbel_draw(u32 k0, u32 k1, u32 jf) {
#if JAX_PARTITIONABLE
  U2 v = tf2x32(k0, k1, 0u, jf);
  u32 bits = v.a ^ v.b;
#else
  u32 bits;
  if (jf < 65536u) { U2 v = tf2x32(k0, k1, jf, jf + 65536u); bits = v.a; }
  else             { U2 v = tf2x32(k0, k1, jf - 65536u, jf); bits = v.b; }
#endif
  float f = __uint_as_float((bits >> 9) | 0x3f800000u) - 1.0f;
  float u = f + 1e-20f;
  u = fmaxf(u, 1e-20f);
  return -logf(-logf(u));
}

__device__ __forceinline__ float fdot2f(half2v a, half2v b, float c) {
#if __has_builtin(__builtin_amdgcn_fdot2)
  return __builtin_amdgcn_fdot2(a, b, c, false);
#else
  return c + (float)a.x * (float)b.x + (float)a.y * (float)b.y;
#endif
}

// ---------------------------------------------------------------------------
// K1 (grid 290 x 512 thr):
//   blocks 0..255  : xf0[b] = ar0[b]@W1 + b1 + relu(um[a[b]]@Wf + bf)  (split-k x2)
//   blocks 256..287: Wq row r = Wp[r]@W1                                (split-k x2)
//   block 288      : cvec = bp@W1                                       (split-k x2)
//   block 289      : pack Wk fp32 -> f16 pairs into ws[WS_WK2]
// ---------------------------------------------------------------------------
__global__ __launch_bounds__(512) void suh_prep(
    const float* __restrict__ ar0, const int* __restrict__ act,
    const float* __restrict__ Wf, const float* __restrict__ bfv,
    const float* __restrict__ W1, const float* __restrict__ b1,
    const float* __restrict__ Wp, const float* __restrict__ bp,
    const float* __restrict__ Wk, const float* __restrict__ umt,
    float* __restrict__ ws)
{
  __shared__ float lvec[1024];
  __shared__ float red2[512];
  __shared__ float feL[256];
  __shared__ float lum[256];
  const int t = threadIdx.x;
  const int bid = blockIdx.x;

  if (bid == NB + 33) return;   // unreachable guard

  if (bid == NB + 33 - 0 || bid == 289) {        // Wk f16 pack
    half2v* wkp = (half2v*)(ws + WS_WK2);
    #pragma unroll
    for (int i = 0; i < 8; ++i) {
      const int p = t * 8 + i;
      const int c2 = p >> 5, h = p & 31;
      half2v v = { (_Float16)Wk[c2 * 64 + h], (_Float16)Wk[c2 * 64 + 32 + h] };
      wkp[p] = v;
    }
    return;
  }

  const int o = t & 255, hf = t >> 8;
  const float* src;
  if (bid < NB) src = ar0 + bid * 1024;
  else if (bid < NB + 32) src = Wp + (bid - NB) * 1024;
  else src = bp;

  for (int i = t; i < 1024; i += 512) lvec[i] = src[i];
  if (bid < NB && t < 256) lum[t] = umt[act[bid] * 256 + t];
  __syncthreads();

  float p = 0.0f;
  const int kb = hf * 512;
  #pragma unroll 16
  for (int k = 0; k < 512; ++k) p = fmaf(lvec[kb + k], W1[(kb + k) * 256 + o], p);
  red2[hf * 256 + o] = p;
  if (bid < NB && hf == 1) {
    float fe = bfv[o];
    #pragma unroll 8
    for (int k = 0; k < 256; ++k) fe = fmaf(lum[k], Wf[k * 256 + o], fe);
    feL[o] = fmaxf(fe, 0.0f);
  }
  __syncthreads();

  if (t < 256) {
    const float s = red2[t] + red2[256 + t];
    if (bid < NB)            ws[WS_XF0 + bid * 256 + t] = s + b1[t] + feL[t];
    else if (bid < NB + 32)  ws[WS_WQ + (bid - NB) * 256 + t] = s;
    else                     ws[WS_CV + t] = s;
  }
}

// ---------------------------------------------------------------------------
// K2: one block per batch row; 64 autoregressive steps, 5 barriers/step.
// ---------------------------------------------------------------------------
__global__ __launch_bounds__(512, 2) void suh_main(
    const float* __restrict__ ar0, const int* __restrict__ act,
    const float* __restrict__ emb, const float* __restrict__ bk,
    const float* __restrict__ W2, const float* __restrict__ b2,
    const float* __restrict__ Wx, const float* __restrict__ Wh,
    const float* __restrict__ bl, const float* __restrict__ Wp,
    const float* __restrict__ bp, const float* __restrict__ selt,
    const float* __restrict__ ws, float* __restrict__ outp)
{
  const int b = blockIdx.x;
  const int t = threadIdx.x;
  const float sel = selt[act[b]];
  float* outL = outp;
  float* outU = outp + OFF_UNITS;
  float* outA = outp + OFF_AR;

  if (sel == 0.0f) {
    float4 z4 = {0.0f, 0.0f, 0.0f, 0.0f};
    float4* pl = (float4*)(outL + (size_t)b * 32768);
    for (int i = t; i < 8192; i += 512) pl[i] = z4;
    if (t < 16) ((float4*)(outU + b * 64))[t] = z4;
    if (t < 256) ((float4*)(outA + b * 1024))[t] = z4;
    return;
  }

  __shared__ __align__(16) _Float16 kph[NE * KPW];  // 40 KB, f16 key_proj
  __shared__ float wq[8192];                         // 32 KB, Wq = Wp@W1
  __shared__ __align__(16) float xf[256];
  __shared__ float maskv[NE];
  __shared__ float red[512];
  __shared__ float cvs[256];
  __shared__ float gumL[64];
  __shared__ float sacc[32];
  __shared__ __align__(16) half2v h2b[16];
  __shared__ float wsum[8];
  __shared__ float wargv[8];
  __shared__ int   wargi[8];

  // ---- per-thread / wave0 register-resident weights ------------------------
  const int hh = t & 31, kc = t >> 5;    // phase A mapping
  float w2r[16];
  #pragma unroll
  for (int i = 0; i < 16; ++i) w2r[i] = W2[(kc * 16 + i) * 32 + hh];

  float wx0[32], wx1[32], wh0[32], wh1[32];
  float blv0 = 0.0f, blv1 = 0.0f, b2v = 0.0f;
  float hv = 0.0f, cv = 0.0f;            // LSTM state, lanes 0..31 of wave0
  if (t < 64) {
    const int c0 = t, c1 = 64 + t;
    #pragma unroll
    for (int r = 0; r < 32; ++r) {
      wx0[r] = Wx[r * 128 + c0]; wx1[r] = Wx[r * 128 + c1];
      wh0[r] = Wh[r * 128 + c0]; wh1[r] = Wh[r * 128 + c1];
    }
    blv0 = bl[c0]; blv1 = bl[c1]; b2v = b2[t & 31];
  }

  if (t < 256) {
    xf[t] = ws[WS_XF0 + b * 256 + t];
    cvs[t] = ws[WS_CV + t];
    #pragma unroll
    for (int i = 0; i < 8; ++i) wq[i * 1024 + (t & 255) * 4 + (i & 0)] = 0.0f; // placeholder overwritten below
  }
  // Wq -> LDS (coalesced float4)
  {
    const float4* s4 = (const float4*)(ws + WS_WQ);
    float4* d4 = (float4*)wq;
    for (int i = t; i < 2048; i += 512) d4[i] = s4[i];
  }
  if (t < 32) sacc[t] = 0.0f;
  maskv[t] = 1.0f;

  // ---- key_proj row e=t via fdot2 (f16 emb x f16 Wk, f32 accum) -----------
  {
    float acc[32];
    #pragma unroll
    for (int h = 0; h < 32; ++h) acc[h] = bk[h];
    const float4* erow = (const float4*)(emb + (size_t)b * (NE * 256) + (size_t)t * 256);
    const half2v* wkg = (const half2v*)(ws + WS_WK2);
    for (int c4 = 0; c4 < 64; ++c4) {
      float4 ev = erow[c4];
      half2v e01 = { (_Float16)ev.x, (_Float16)ev.y };
      half2v e23 = { (_Float16)ev.z, (_Float16)ev.w };
      const half2v* w0 = wkg + (2 * c4) * 32;
      const half2v* w1 = w0 + 32;
      #pragma unroll
      for (int h = 0; h < 32; ++h) {
        acc[h] = fdot2f(e01, w0[h], acc[h]);
        acc[h] = fdot2f(e23, w1[h], acc[h]);
      }
    }
    half2v* kr = (half2v*)(kph + t * KPW);
    #pragma unroll
    for (int j = 0; j < 16; ++j) {
      half2v v = { (_Float16)acc[2 * j], (_Float16)acc[2 * j + 1] };
      kr[j] = v;
    }
  }
  __syncthreads();

  const u32 jf_own = (u32)(b * 512 + t);

  for (int step = 0; step < NT; ++step) {
    const u32 sk0 = SUBTAB.s0[step], sk1 = SUBTAB.s1[step];
    float gum = 0.0f;
    if (t >= 64) gum = gumbel_draw(sk0, sk1, jf_own);
    if (t >= 64 && t < 128) gumL[t - 64] = gumbel_draw(sk0, sk1, jf_own - 64u);

    // ---- A: z2 partials: relu(xf) @ W2 ------------------------------------
    {
      float pa = 0.0f;
      const float* xk = &xf[kc * 16];
      #pragma unroll
      for (int i = 0; i < 16; ++i) pa = fmaf(fmaxf(xk[i], 0.0f), w2r[i], pa);
      red[kc * 32 + hh] = pa;
    }
    __syncthreads();                                   // B1

    // ---- B: wave0 only: z2 reduce + LSTM ----------------------------------
    if (t < 64) {
      const int h = t & 31, half = t >> 5;
      float z = 0.0f;
      #pragma unroll
      for (int i = 0; i < 8; ++i) z += red[(half * 8 + i) * 32 + h];
      z += __shfl_xor(z, 32);
      const float z2v = z + b2v;

      float g0 = blv0, g1 = blv1;
      #pragma unroll
      for (int r = 0; r < 32; ++r) {
        const float zr = __shfl(z2v, r);
        const float hr = __shfl(hv, r);
        g0 = fmaf(zr, wx0[r], g0); g0 = fmaf(hr, wh0[r], g0);
        g1 = fmaf(zr, wx1[r], g1); g1 = fmaf(hr, wh1[r], g1);
      }
      const float zf = __shfl_xor(g0, 32);
      const float zo = __shfl_xor(g1, 32);
      if (t < 32) {
        const float si = 1.0f / (1.0f + expf(-g0));
        const float sf = 1.0f / (1.0f + expf(-zf));
        const float so = 1.0f / (1.0f + expf(-zo));
        cv = sf * cv + si * tanhf(g1);
        hv = so * tanhf(cv);
      }
      const float ha = __shfl(hv, 2 * (t & 31));
      const float hb = __shfl(hv, 2 * (t & 31) + 1);
      if (t < 16) { half2v v = { (_Float16)ha, (_Float16)hb }; h2b[t] = v; }
    }
    __syncthreads();                                   // B2

    // ---- C: logits, exp, sum ----------------------------------------------
    if (t < 64) gum = gumL[t];
    float yv = 0.0f;
    {
      const half2v* k2 = (const half2v*)(kph + t * KPW);
      #pragma unroll
      for (int j = 0; j < 16; ++j) yv = fdot2f(k2[j], h2b[j], yv);
    }
    const float y2 = yv * maskv[t];
    outL[(size_t)b * 32768 + step * 512 + t] = y2;
    const float ev = expf(y2);
    float sv = ev;
    #pragma unroll
    for (int s = 1; s < 64; s <<= 1) sv += __shfl_xor(sv, s);
    if ((t & 63) == 0) wsum[t >> 6] = sv;
    __syncthreads();                                   // B3

    float Z = wsum[0];
    #pragma unroll
    for (int i = 1; i < 8; ++i) Z += wsum[i];
    float val = ev / Z + gum;
    int idx = t;
    #pragma unroll
    for (int s = 1; s < 64; s <<= 1) {
      const float vo = __shfl_xor(val, s);
      const int io = __shfl_xor(idx, s);
      if (vo > val || (vo == val && io < idx)) { val = vo; idx = io; }
    }
    if ((t & 63) == 0) { wargv[t >> 6] = val; wargi[t >> 6] = idx; }
    __syncthreads();                                   // B4

    float bvv = wargv[0]; int id = wargi[0];
    #pragma unroll
    for (int i = 1; i < 8; ++i) {
      if (wargv[i] > bvv || (wargv[i] == bvv && wargi[i] < id)) { bvv = wargv[i]; id = wargi[i]; }
    }

    // ---- D: mask, outputs, xf feedback ------------------------------------
    if (t == 0) { maskv[id] = 0.0f; outU[b * 64 + step] = (float)id; }
    if (t < 32) sacc[t] += (float)kph[id * KPW + t] - 0.001953125f;
    if (t < 256) {
      const half2v* kid = (const half2v*)(kph + id * KPW);
      float dx = cvs[t];
      #pragma unroll
      for (int j = 0; j < 16; ++j) {
        half2v kj = kid[j];
        dx = fmaf((float)kj.x - 0.001953125f, wq[(2 * j) * 256 + t], dx);
        dx = fmaf((float)kj.y - 0.001953125f, wq[(2 * j + 1) * 256 + t], dx);
      }
      xf[t] += dx;
    }
    __syncthreads();                                   // B5
  }

  // ---- epilogue: ar = ar0 + sacc@Wp + 64*bp --------------------------------
  for (int j = t; j < 1024; j += 512) {
    float acc2 = ar0[b * 1024 + j] + 64.0f * bp[j];
    #pragma unroll 8
    for (int r = 0; r < 32; ++r) acc2 = fmaf(sacc[r], Wp[r * 1024 + j], acc2);
    outA[b * 1024 + j] = acc2;
  }
}

extern "C" void kernel_launch(void* const* d_in, const int* in_sizes, int n_in,
                              void* d_out, int out_size, void* d_ws, size_t ws_size,
                              hipStream_t stream)
{
  (void)in_sizes; (void)n_in; (void)out_size; (void)ws_size;
  const float* ar0 = (const float*)d_in[0];
  const int*   act = (const int*)d_in[1];
  const float* emb = (const float*)d_in[2];
  const float* Wf  = (const float*)d_in[3];
  const float* bfv = (const float*)d_in[4];
  const float* Wk  = (const float*)d_in[5];
  const float* bk  = (const float*)d_in[6];
  const float* W1  = (const float*)d_in[7];
  const float* b1  = (const float*)d_in[8];
  const float* W2  = (const float*)d_in[9];
  const float* b2  = (const float*)d_in[10];
  const float* Wx  = (const float*)d_in[11];
  const float* Wh  = (const float*)d_in[12];
  const float* bl  = (const float*)d_in[13];
  const float* Wp  = (const float*)d_in[14];
  const float* bp  = (const float*)d_in[15];
  const float* umt = (const float*)d_in[16];
  const float* selt = (const float*)d_in[17];
  float* ws = (float*)d_ws;
  float* outp = (float*)d_out;

  suh_prep<<<dim3(290), dim3(512), 0, stream>>>(ar0, act, Wf, bfv, W1, b1, Wp, bp, Wk, umt, ws);
  suh_main<<<dim3(256), dim3(512), 0, stream>>>(ar0, act, emb, bk, W2, b2, Wx, Wh,
                                                bl, Wp, bp, selt, ws, outp);
}

// Round 4
// 539.994 us; speedup vs baseline: 1.1253x; 1.0350x over previous
//
#include <hip/hip_runtime.h>

// ---------------------------------------------------------------------------
// SelectedUnitsHead (AlphaStar-style pointer head), MI355X / gfx950
// B=256 rows, E=512 entities, 64 autoregressive steps.
// One persistent block (512 thr) per batch row. d_out is fp32.
// v4: fixed Wk-pack guard bug (r3 ran with poisoned Wk!); gumbel precompute
//     kernel (RNG out of serial loop); LSTM weights f16 in LDS (kills scratch
//     spill, VGPR was 128 < declared arrays); transposed kp LDS layout
//     (kills 8-way ds_read conflicts); lgkmcnt-only barriers (skip vmcnt
//     drain of logit stores); __expf/__logf fast paths.
// ---------------------------------------------------------------------------

#define JAX_PARTITIONABLE 1

typedef unsigned int u32;
typedef _Float16 half2v __attribute__((ext_vector_type(2)));

#define NB 256
#define NE 512
#define NT 64

#define OFF_UNITS 8388608      // 256*64*512   (fp32 elements)
#define OFF_AR    8404992      // + 256*64     (fp32 elements)

// ws layout (float units):
//   Wq[8192] | cvec[256] | xf0[65536] | wk2[4096] | gumbels[8388608]
#define WS_WQ   0
#define WS_CV   8192
#define WS_XF0  8448
#define WS_WK2  73984
#define WS_GU   78080

// barrier with LDS-visibility only (no vmcnt drain of in-flight global stores)
#define BARL() asm volatile("s_waitcnt lgkmcnt(0)\n\ts_barrier" ::: "memory")

struct U2 { u32 a, b; };

__host__ __device__ constexpr u32 rotl32(u32 x, int r) {
  return (x << r) | (x >> (32 - r));
}

__host__ __device__ constexpr U2 tf2x32(u32 k0, u32 k1, u32 x0, u32 x1) {
  u32 ks2 = k0 ^ k1 ^ 0x1BD11BDAu;
  x0 += k0; x1 += k1;
  x0 += x1; x1 = rotl32(x1, 13); x1 ^= x0;
  x0 += x1; x1 = rotl32(x1, 15); x1 ^= x0;
  x0 += x1; x1 = rotl32(x1, 26); x1 ^= x0;
  x0 += x1; x1 = rotl32(x1, 6);  x1 ^= x0;
  x0 += k1; x1 += ks2 + 1u;
  x0 += x1; x1 = rotl32(x1, 17); x1 ^= x0;
  x0 += x1; x1 = rotl32(x1, 29); x1 ^= x0;
  x0 += x1; x1 = rotl32(x1, 16); x1 ^= x0;
  x0 += x1; x1 = rotl32(x1, 24); x1 ^= x0;
  x0 += ks2; x1 += k0 + 2u;
  x0 += x1; x1 = rotl32(x1, 13); x1 ^= x0;
  x0 += x1; x1 = rotl32(x1, 15); x1 ^= x0;
  x0 += x1; x1 = rotl32(x1, 26); x1 ^= x0;
  x0 += x1; x1 = rotl32(x1, 6);  x1 ^= x0;
  x0 += k0; x1 += k1 + 3u;
  x0 += x1; x1 = rotl32(x1, 17); x1 ^= x0;
  x0 += x1; x1 = rotl32(x1, 29); x1 ^= x0;
  x0 += x1; x1 = rotl32(x1, 16); x1 ^= x0;
  x0 += x1; x1 = rotl32(x1, 24); x1 ^= x0;
  x0 += k1; x1 += ks2 + 4u;
  x0 += x1; x1 = rotl32(x1, 13); x1 ^= x0;
  x0 += x1; x1 = rotl32(x1, 15); x1 ^= x0;
  x0 += x1; x1 = rotl32(x1, 26); x1 ^= x0;
  x0 += x1; x1 = rotl32(x1, 6);  x1 ^= x0;
  x0 += ks2; x1 += k0 + 5u;
  return U2{x0, x1};
}

struct KeyTab { u32 s0[NT]; u32 s1[NT]; };

__host__ __device__ constexpr KeyTab make_tab() {
  KeyTab t{};
  u32 k0 = 0u, k1 = 42u;
  for (int i = 0; i < NT; ++i) {
#if JAX_PARTITIONABLE
    U2 nk = tf2x32(k0, k1, 0u, 0u);
    U2 sb = tf2x32(k0, k1, 0u, 1u);
#else
    U2 r02 = tf2x32(k0, k1, 0u, 2u);
    U2 r13 = tf2x32(k0, k1, 1u, 3u);
    U2 nk{r02.a, r13.a};
    U2 sb{r02.b, r13.b};
#endif
    t.s0[i] = sb.a; t.s1[i] = sb.b;
    k0 = nk.a; k1 = nk.b;
  }
  return t;
}

__constant__ KeyTab SUBTAB = make_tab();

__device__ __forceinline__ float gumbel_draw(u32 k0, u32 k1, u32 jf) {
#if JAX_PARTITIONABLE
  U2 v = tf2x32(k0, k1, 0u, jf);
  u32 bits = v.a ^ v.b;
#else
  u32 bits;
  if (jf < 65536u) { U2 v = tf2x32(k0, k1, jf, jf + 65536u); bits = v.a; }
  else             { U2 v = tf2x32(k0, k1, jf - 65536u, jf); bits = v.b; }
#endif
  float f = __uint_as_float((bits >> 9) | 0x3f800000u) - 1.0f;
  float u = f + 1e-20f;
  u = fmaxf(u, 1e-20f);
  return -__logf(-__logf(u));
}

__device__ __forceinline__ float fdot2f(half2v a, half2v b, float c) {
#if __has_builtin(__builtin_amdgcn_fdot2)
  return __builtin_amdgcn_fdot2(a, b, c, false);
#else
  return c + (float)a.x * (float)b.x + (float)a.y * (float)b.y;
#endif
}

// ---------------------------------------------------------------------------
// K0: gumbel precompute — one thread per (b, step, e) draw, active rows only.
// grid 16384 x 512: blk = b*64 + step, tid = e.
// ---------------------------------------------------------------------------
__global__ __launch_bounds__(512) void suh_gum(
    const int* __restrict__ act, const float* __restrict__ selt,
    float* __restrict__ gws)
{
  const u32 blk = blockIdx.x;
  const int b = (int)(blk >> 6), step = (int)(blk & 63u);
  if (selt[act[b]] == 0.0f) return;
  const int e = threadIdx.x;
  gws[((size_t)blk << 9) | (u32)e] =
      gumbel_draw(SUBTAB.s0[step], SUBTAB.s1[step], (u32)(b * 512 + e));
}

// ---------------------------------------------------------------------------
// K1 (grid 290 x 512 thr):
//   blocks 0..255  : xf0[b] = ar0[b]@W1 + b1 + relu(um[a[b]]@Wf + bf)
//   blocks 256..287: Wq row r = Wp[r]@W1
//   block 288      : cvec = bp@W1
//   block 289      : pack Wk fp32 -> f16 pairs into ws[WS_WK2]   (r3 BUG FIXED)
// ---------------------------------------------------------------------------
__global__ __launch_bounds__(512) void suh_prep(
    const float* __restrict__ ar0, const int* __restrict__ act,
    const float* __restrict__ Wf, const float* __restrict__ bfv,
    const float* __restrict__ W1, const float* __restrict__ b1,
    const float* __restrict__ Wp, const float* __restrict__ bp,
    const float* __restrict__ Wk, const float* __restrict__ umt,
    float* __restrict__ ws)
{
  __shared__ float lvec[1024];
  __shared__ float red2[512];
  __shared__ float feL[256];
  __shared__ float lum[256];
  const int t = threadIdx.x;
  const int bid = blockIdx.x;

  if (bid >= 289) {                      // block 289: Wk f16 pack (runs now!)
    half2v* wkp = (half2v*)(ws + WS_WK2);
    #pragma unroll
    for (int i = 0; i < 8; ++i) {
      const int p = t * 8 + i;           // p in [0,4096)
      const int c2 = p >> 5, h = p & 31; // channel pair c2 -> (2c2, 2c2+1)
      half2v v = { (_Float16)Wk[c2 * 64 + h], (_Float16)Wk[c2 * 64 + 32 + h] };
      wkp[p] = v;
    }
    return;
  }

  const int o = t & 255, hf = t >> 8;
  const float* src;
  if (bid < NB) src = ar0 + bid * 1024;
  else if (bid < NB + 32) src = Wp + (bid - NB) * 1024;
  else src = bp;

  for (int i = t; i < 1024; i += 512) lvec[i] = src[i];
  if (bid < NB && t < 256) lum[t] = umt[act[bid] * 256 + t];
  __syncthreads();

  float p = 0.0f;
  const int kb = hf * 512;
  #pragma unroll 16
  for (int k = 0; k < 512; ++k) p = fmaf(lvec[kb + k], W1[(kb + k) * 256 + o], p);
  red2[hf * 256 + o] = p;
  if (bid < NB && hf == 1) {
    float fe = bfv[o];
    #pragma unroll 8
    for (int k = 0; k < 256; ++k) fe = fmaf(lum[k], Wf[k * 256 + o], fe);
    feL[o] = fmaxf(fe, 0.0f);
  }
  __syncthreads();

  if (t < 256) {
    const float s = red2[t] + red2[256 + t];
    if (bid < NB)            ws[WS_XF0 + bid * 256 + t] = s + b1[t] + feL[t];
    else if (bid < NB + 32)  ws[WS_WQ + (bid - NB) * 256 + t] = s;
    else                     ws[WS_CV + t] = s;
  }
}

// ---------------------------------------------------------------------------
// K2: one block per batch row; 64 autoregressive steps, 5 light barriers/step.
// ---------------------------------------------------------------------------
__global__ __launch_bounds__(512, 1) void suh_main(
    const float* __restrict__ ar0, const int* __restrict__ act,
    const float* __restrict__ emb, const float* __restrict__ bk,
    const float* __restrict__ W2, const float* __restrict__ b2,
    const float* __restrict__ Wx, const float* __restrict__ Wh,
    const float* __restrict__ bl, const float* __restrict__ Wp,
    const float* __restrict__ bp, const float* __restrict__ selt,
    const float* __restrict__ ws, const float* __restrict__ gws,
    const int use_pre, float* __restrict__ outp)
{
  const int b = blockIdx.x;
  const int t = threadIdx.x;
  const float sel = selt[act[b]];
  float* outL = outp;
  float* outU = outp + OFF_UNITS;
  float* outA = outp + OFF_AR;

  if (sel == 0.0f) {
    float4 z4 = {0.0f, 0.0f, 0.0f, 0.0f};
    float4* pl = (float4*)(outL + (size_t)b * 32768);
    for (int i = t; i < 8192; i += 512) pl[i] = z4;
    if (t < 16) ((float4*)(outU + b * 64))[t] = z4;
    if (t < 256) ((float4*)(outA + b * 1024))[t] = z4;
    return;
  }

  __shared__ half2v kpT[16][NE];        // 32 KB transposed kp: [h-pair][entity]
  __shared__ float wq[32][256];         // 32 KB Wq = Wp@W1
  __shared__ half2v whx[4096];          // 16 KB {Wx,Wh} pairs: [r][gatecol]
  __shared__ float xf[256];
  __shared__ float maskv[NE];
  __shared__ float red[512];
  __shared__ float cvs[256];
  __shared__ float sacc[32];
  __shared__ half2v h2b[16];
  __shared__ float wsum[8];
  __shared__ float wargv[8];
  __shared__ int   wargi[8];

  // ---- per-thread register weights (phase A) ------------------------------
  const int hh = t & 31, kc = t >> 5;
  float w2r[16];
  #pragma unroll
  for (int i = 0; i < 16; ++i) w2r[i] = W2[(kc * 16 + i) * 32 + hh];

  float blv0 = 0.0f, blv1 = 0.0f, b2v = 0.0f;
  float hv = 0.0f, cv = 0.0f;           // LSTM state in wave0 lanes 0..31
  if (t < 64) { blv0 = bl[t]; blv1 = bl[64 + t]; b2v = b2[t & 31]; }

  // ---- LDS fills ----------------------------------------------------------
  for (int i = t; i < 4096; i += 512) {
    const int r = i >> 7, g = i & 127;
    half2v v = { (_Float16)Wx[r * 128 + g], (_Float16)Wh[r * 128 + g] };
    whx[i] = v;
  }
  {
    const float4* s4 = (const float4*)(ws + WS_WQ);
    float4* d4 = (float4*)&wq[0][0];
    for (int i = t; i < 2048; i += 512) d4[i] = s4[i];
  }
  if (t < 256) { xf[t] = ws[WS_XF0 + b * 256 + t]; cvs[t] = ws[WS_CV + t]; }
  if (t < 32) sacc[t] = 0.0f;
  maskv[t] = 1.0f;

  // ---- key_proj row e=t via fdot2, written transposed ---------------------
  {
    float acc[32];
    #pragma unroll
    for (int h = 0; h < 32; ++h) acc[h] = bk[h];
    const float4* erow = (const float4*)(emb + (size_t)b * (NE * 256) + (size_t)t * 256);
    const half2v* wkg = (const half2v*)(ws + WS_WK2);
    for (int c4 = 0; c4 < 64; ++c4) {
      float4 ev = erow[c4];
      half2v e01 = { (_Float16)ev.x, (_Float16)ev.y };
      half2v e23 = { (_Float16)ev.z, (_Float16)ev.w };
      const half2v* w0 = wkg + (2 * c4) * 32;
      const half2v* w1 = w0 + 32;
      #pragma unroll
      for (int h = 0; h < 32; ++h) {
        acc[h] = fdot2f(e01, w0[h], acc[h]);
        acc[h] = fdot2f(e23, w1[h], acc[h]);
      }
    }
    #pragma unroll
    for (int j = 0; j < 16; ++j) {
      half2v v = { (_Float16)acc[2 * j], (_Float16)acc[2 * j + 1] };
      kpT[j][t] = v;
    }
  }
  __syncthreads();

  const size_t gbase = (size_t)b * 64 * 512 + t;

  for (int step = 0; step < NT; ++step) {
    // gumbel: precomputed load (issued early, used after B3) or fallback
    float gum;
    if (use_pre) gum = gws[gbase + (size_t)step * 512];
    else gum = gumbel_draw(SUBTAB.s0[step], SUBTAB.s1[step], (u32)(b * 512 + t));

    // ---- A: z2 partials: relu(xf) @ W2 ------------------------------------
    {
      float pa = 0.0f;
      const float* xk = &xf[kc * 16];
      #pragma unroll
      for (int i = 0; i < 16; ++i) pa = fmaf(fmaxf(xk[i], 0.0f), w2r[i], pa);
      red[kc * 32 + hh] = pa;
    }
    BARL();                                            // B1

    // ---- B: wave0: z2 reduce + LSTM (weights from LDS, f16 pairs) ---------
    if (t < 64) {
      const int h = t & 31, half = t >> 5;
      float z = 0.0f;
      #pragma unroll
      for (int i = 0; i < 8; ++i) z += red[(half * 8 + i) * 32 + h];
      z += __shfl_xor(z, 32);
      const float z2v = z + b2v;

      float g0 = blv0, g1 = blv1;
      #pragma unroll
      for (int r = 0; r < 32; ++r) {
        const float zr = __shfl(z2v, r);
        const float hr = __shfl(hv, r);
        half2v p0 = whx[r * 128 + t];
        half2v p1 = whx[r * 128 + 64 + t];
        g0 = fmaf(zr, (float)p0.x, g0); g0 = fmaf(hr, (float)p0.y, g0);
        g1 = fmaf(zr, (float)p1.x, g1); g1 = fmaf(hr, (float)p1.y, g1);
      }
      const float zf = __shfl_xor(g0, 32);
      const float zo = __shfl_xor(g1, 32);
      if (t < 32) {
        const float si = 1.0f / (1.0f + __expf(-g0));
        const float sf = 1.0f / (1.0f + __expf(-zf));
        const float so = 1.0f / (1.0f + __expf(-zo));
        cv = sf * cv + si * tanhf(g1);
        hv = so * tanhf(cv);
      }
      const float ha = __shfl(hv, 2 * (t & 31));
      const float hb = __shfl(hv, 2 * (t & 31) + 1);
      if (t < 16) { half2v v = { (_Float16)ha, (_Float16)hb }; h2b[t] = v; }
    }
    BARL();                                            // B2

    // ---- C: logits (conflict-free kpT), exp, per-wave sum -----------------
    float a0 = 0.0f, a1 = 0.0f, a2 = 0.0f, a3 = 0.0f;
    #pragma unroll
    for (int j = 0; j < 16; j += 4) {
      a0 = fdot2f(kpT[j][t],     h2b[j],     a0);
      a1 = fdot2f(kpT[j + 1][t], h2b[j + 1], a1);
      a2 = fdot2f(kpT[j + 2][t], h2b[j + 2], a2);
      a3 = fdot2f(kpT[j + 3][t], h2b[j + 3], a3);
    }
    const float y2 = ((a0 + a1) + (a2 + a3)) * maskv[t];
    outL[(size_t)b * 32768 + step * 512 + t] = y2;
    const float ev = __expf(y2);
    float sv = ev;
    #pragma unroll
    for (int s = 1; s < 64; s <<= 1) sv += __shfl_xor(sv, s);
    if ((t & 63) == 0) wsum[t >> 6] = sv;
    BARL();                                            // B3

    float Z = wsum[0];
    #pragma unroll
    for (int i = 1; i < 8; ++i) Z += wsum[i];
    float val = ev / Z + gum;
    int idx = t;
    #pragma unroll
    for (int s = 1; s < 64; s <<= 1) {
      const float vo = __shfl_xor(val, s);
      const int io = __shfl_xor(idx, s);
      if (vo > val || (vo == val && io < idx)) { val = vo; idx = io; }
    }
    if ((t & 63) == 0) { wargv[t >> 6] = val; wargi[t >> 6] = idx; }
    BARL();                                            // B4

    float bvv = wargv[0]; int id = wargi[0];
    #pragma unroll
    for (int i = 1; i < 8; ++i) {
      if (wargv[i] > bvv || (wargv[i] == bvv && wargi[i] < id)) { bvv = wargv[i]; id = wargi[i]; }
    }

    // ---- D: mask, outputs, xf feedback ------------------------------------
    if (t == 0) { maskv[id] = 0.0f; outU[b * 64 + step] = (float)id; }
    if (t < 32) {
      half2v kj = kpT[t >> 1][id];
      const float kv = (t & 1) ? (float)kj.y : (float)kj.x;
      sacc[t] += kv - 0.001953125f;
    }
    if (t < 256) {
      float dx = cvs[t];
      #pragma unroll
      for (int j = 0; j < 16; ++j) {
        half2v kj = kpT[j][id];
        dx = fmaf((float)kj.x - 0.001953125f, wq[2 * j][t], dx);
        dx = fmaf((float)kj.y - 0.001953125f, wq[2 * j + 1][t], dx);
      }
      xf[t] += dx;
    }
    BARL();                                            // B5
  }

  // ---- epilogue: ar = ar0 + sacc@Wp + 64*bp -------------------------------
  for (int j = t; j < 1024; j += 512) {
    float acc2 = ar0[b * 1024 + j] + 64.0f * bp[j];
    #pragma unroll 8
    for (int r = 0; r < 32; ++r) acc2 = fmaf(sacc[r], Wp[r * 1024 + j], acc2);
    outA[b * 1024 + j] = acc2;
  }
}

extern "C" void kernel_launch(void* const* d_in, const int* in_sizes, int n_in,
                              void* d_out, int out_size, void* d_ws, size_t ws_size,
                              hipStream_t stream)
{
  (void)in_sizes; (void)n_in; (void)out_size;
  const float* ar0 = (const float*)d_in[0];
  const int*   act = (const int*)d_in[1];
  const float* emb = (const float*)d_in[2];
  const float* Wf  = (const float*)d_in[3];
  const float* bfv = (const float*)d_in[4];
  const float* Wk  = (const float*)d_in[5];
  const float* bk  = (const float*)d_in[6];
  const float* W1  = (const float*)d_in[7];
  const float* b1  = (const float*)d_in[8];
  const float* W2  = (const float*)d_in[9];
  const float* b2  = (const float*)d_in[10];
  const float* Wx  = (const float*)d_in[11];
  const float* Wh  = (const float*)d_in[12];
  const float* bl  = (const float*)d_in[13];
  const float* Wp  = (const float*)d_in[14];
  const float* bp  = (const float*)d_in[15];
  const float* umt = (const float*)d_in[16];
  const float* selt = (const float*)d_in[17];
  float* ws = (float*)d_ws;
  float* outp = (float*)d_out;

  const size_t need = (size_t)(WS_GU + 8388608) * sizeof(float);
  const int use_pre = (ws_size >= need) ? 1 : 0;

  suh_prep<<<dim3(290), dim3(512), 0, stream>>>(ar0, act, Wf, bfv, W1, b1, Wp, bp, Wk, umt, ws);
  if (use_pre)
    suh_gum<<<dim3(16384), dim3(512), 0, stream>>>(act, selt, ws + WS_GU);
  suh_main<<<dim3(256), dim3(512), 0, stream>>>(ar0, act, emb, bk, W2, b2, Wx, Wh,
                                                bl, Wp, bp, selt, ws, ws + WS_GU,
                                                use_pre, outp);
}